// Round 7
// baseline (110.726 us; speedup 1.0000x reference)
//
#include <hip/hip_runtime.h>

// PCEN with 10 smoothing rates. x:(B,F,T) f32 -> out:(B,R,F,T) f32
//
// One wave owns one (b,rate,f) row (rate-major mapping). Recurrence
// y_t = a*y_{t-1} + s*x_t, y_0 = x_0 (seed carry=x_0, a+s=1).
//
// R7 = R6 (dense 1KB-per-instruction loads/stores, dual-chain scan) with
// CACHED stores instead of nontemporal. A/B history:
//   R3 lane*8 + nt          : 90.8us   (nt path ~4 TB/s, density-insensitive)
//   R5 lane*8 + cached      : 117us    (partial-line write-allocate RMW)
//   R6 lane*4-dense + nt    : 91.5us   (nt path saturates regardless)
//   R7 lane*4-dense + cached: predict 58-70us (full-line coverage -> no RMW,
//                             fill-kernel-like 6.9 TB/s writeback path)

typedef float f32x4 __attribute__((ext_vector_type(4)));

constexpr int B_ = 16, F_ = 128, T_ = 4000, R_ = 10;
constexpr float EPS_ = 1e-5f;
constexpr int TPB = 256;            // 4 waves / block
constexpr int WPB = TPB / 64;

__global__ __launch_bounds__(TPB) void pcen_kernel(
    const float* __restrict__ x,
    const float* __restrict__ s_log,
    const float* __restrict__ alpha_log,
    const float* __restrict__ delta_log,
    const float* __restrict__ r_log,
    float* __restrict__ out)
{
    const int wid  = blockIdx.x * WPB + (threadIdx.x >> 6);
    const int lane = threadIdx.x & 63;

    // rate-major: wid = ((b*R + rate)*F + f) -> block's 4 waves write 4
    // consecutive 16KB output rows.
    const int b    = wid / (R_ * F_);
    const int rem  = wid - b * (R_ * F_);
    const int rate = rem / F_;
    const int f    = rem - rate * F_;

    const float s     = __builtin_expf(s_log[rate * F_ + f]);
    const float a     = 1.0f - s;
    const float alpha = __builtin_expf(alpha_log[f]);
    const float delta = __builtin_expf(delta_log[f]);
    const float r     = __builtin_expf(r_log[f]);
    const float delta_r = __builtin_exp2f(r * __builtin_log2f(delta));

    const float a2 = a * a, a3 = a2 * a, a4 = a2 * a2;
    const float a8 = a4 * a4, a16 = a8 * a8, a32 = a16 * a16;
    const float a64 = a32 * a32, a128 = a64 * a64, a256 = a128 * a128;

    // per-lane a^(4*lane), exact product over lane bits
    float pl = 1.0f;
    pl *= (lane & 1)  ? a4   : 1.0f;
    pl *= (lane & 2)  ? a8   : 1.0f;
    pl *= (lane & 4)  ? a16  : 1.0f;
    pl *= (lane & 8)  ? a32  : 1.0f;
    pl *= (lane & 16) ? a64  : 1.0f;
    pl *= (lane & 32) ? a128 : 1.0f;

    const float* xrow = x   + (size_t)(b * F_ + f) * T_;
    float*       orow = out + (size_t)((b * R_ + rate) * F_ + f) * T_;

    float carry = xrow[0];   // y_{-1} := x_0  (a+s=1 makes y_0 = x_0)

    auto pcen1 = [&](float xv, float m) -> float {
        const float sm = __builtin_exp2f(-alpha * __builtin_log2f(EPS_ + m));
        return __builtin_exp2f(r * __builtin_log2f(fmaf(xv, sm, delta))) - delta_r;
    };

    for (int t0 = 0; t0 < T_; t0 += 512) {
        const int tA = t0 + lane * 4;
        const int tB = tA + 256;
        const bool actA = (tA < T_);
        const bool actB = (tB < T_);
        float4 vA = make_float4(0.f, 0.f, 0.f, 0.f);
        float4 vB = make_float4(0.f, 0.f, 0.f, 0.f);
        if (actA) vA = *reinterpret_cast<const float4*>(xrow + tA);
        if (actB) vB = *reinterpret_cast<const float4*>(xrow + tB);

        // local zero-init scans (independent)
        const float lA0 = s * vA.x;
        const float lA1 = fmaf(a, lA0, s * vA.y);
        const float lA2 = fmaf(a, lA1, s * vA.z);
        const float lA3 = fmaf(a, lA2, s * vA.w);
        const float lB0 = s * vB.x;
        const float lB1 = fmaf(a, lB0, s * vB.y);
        const float lB2 = fmaf(a, lB1, s * vB.z);
        const float lB3 = fmaf(a, lB2, s * vB.w);

        float YA = lA3;
        if (lane == 0) YA = fmaf(a4, carry, YA);   // fold prev-chunk carry
        float YB = lB3;                             // zero-init chain

        // two interleaved Hillis-Steele scans, segment multiplier a^4
        float uA, uB;
        uA = __shfl_up(YA, 1);  uB = __shfl_up(YB, 1);
        if (lane >= 1)  { YA = fmaf(a4,   uA, YA); YB = fmaf(a4,   uB, YB); }
        uA = __shfl_up(YA, 2);  uB = __shfl_up(YB, 2);
        if (lane >= 2)  { YA = fmaf(a8,   uA, YA); YB = fmaf(a8,   uB, YB); }
        uA = __shfl_up(YA, 4);  uB = __shfl_up(YB, 4);
        if (lane >= 4)  { YA = fmaf(a16,  uA, YA); YB = fmaf(a16,  uB, YB); }
        uA = __shfl_up(YA, 8);  uB = __shfl_up(YB, 8);
        if (lane >= 8)  { YA = fmaf(a32,  uA, YA); YB = fmaf(a32,  uB, YB); }
        uA = __shfl_up(YA, 16); uB = __shfl_up(YB, 16);
        if (lane >= 16) { YA = fmaf(a64,  uA, YA); YB = fmaf(a64,  uB, YB); }
        uA = __shfl_up(YA, 32); uB = __shfl_up(YB, 32);
        if (lane >= 32) { YA = fmaf(a128, uA, YA); YB = fmaf(a128, uB, YB); }

        float yinA = __shfl_up(YA, 1);
        if (lane == 0) yinA = carry;
        float yinB = __shfl_up(YB, 1);
        if (lane == 0) yinB = 0.0f;
        const float exitA = __shfl(YA, 63);
        yinB = fmaf(pl, exitA, yinB);              // link chain B to chain A
        carry = fmaf(a256, exitA, __shfl(YB, 63)); // chunk-exit state

        if (actA) {
            const float mA0 = fmaf(a,  yinA, lA0);
            const float mA1 = fmaf(a2, yinA, lA1);
            const float mA2 = fmaf(a3, yinA, lA2);
            const float mA3 = fmaf(a4, yinA, lA3);
            f32x4 o;
            o.x = pcen1(vA.x, mA0);
            o.y = pcen1(vA.y, mA1);
            o.z = pcen1(vA.z, mA2);
            o.w = pcen1(vA.w, mA3);
            *reinterpret_cast<f32x4*>(orow + tA) = o;   // cached: full-line
        }                                               // coverage -> no RMW
        if (actB) {
            const float mB0 = fmaf(a,  yinB, lB0);
            const float mB1 = fmaf(a2, yinB, lB1);
            const float mB2 = fmaf(a3, yinB, lB2);
            const float mB3 = fmaf(a4, yinB, lB3);
            f32x4 o;
            o.x = pcen1(vB.x, mB0);
            o.y = pcen1(vB.y, mB1);
            o.z = pcen1(vB.z, mB2);
            o.w = pcen1(vB.w, mB3);
            *reinterpret_cast<f32x4*>(orow + tB) = o;
        }
    }
}

extern "C" void kernel_launch(void* const* d_in, const int* in_sizes, int n_in,
                              void* d_out, int out_size, void* d_ws, size_t ws_size,
                              hipStream_t stream) {
    const float* x         = (const float*)d_in[0];
    const float* s_log     = (const float*)d_in[1];
    const float* alpha_log = (const float*)d_in[2];
    const float* delta_log = (const float*)d_in[3];
    const float* r_log     = (const float*)d_in[4];
    float* out = (float*)d_out;

    const int n_waves = B_ * R_ * F_;          // 20480
    const int blocks  = n_waves / WPB;         // 5120
    pcen_kernel<<<blocks, TPB, 0, stream>>>(x, s_log, alpha_log, delta_log, r_log, out);
}

// Round 8
// 108.652 us; speedup vs baseline: 1.0191x; 1.0191x over previous
//
#include <hip/hip_runtime.h>

// PCEN with 10 smoothing rates. x:(B,F,T) f32 -> out:(B,R,F,T) f32
//
// R8: LDS-staged x, 10 waves/block (one rate per wave).
//   Block <-> (b,f). x row chunk (512 floats) staged into LDS double-buffer
//   by threads 0..127; all 10 rate-waves consume from LDS. Cuts global x
//   reads 10x while keeping: 1 rate/wave, 1 write stream/wave, 20480 waves,
//   dense nt stores, dual-chain scan (R6 machinery unchanged).
//   DECISIVE TEST: if x re-reads were real HBM traffic (L3 not serving),
//   this drops total HBM 656->361 MB and dur 91 -> ~65us. If dur unchanged,
//   reads were cache-served and ~91us is the nt-write/DRAM ceiling for this
//   pattern (near-roofline).
// History: R3 nt lane*8=90.8 | R5 cached=117 | R6 nt dense=91.5 | R7 cached
//   dense=110.7. nt insensitive to density & VALU; cached always worse.

typedef float f32x4 __attribute__((ext_vector_type(4)));

constexpr int B_ = 16, F_ = 128, T_ = 4000, R_ = 10;
constexpr float EPS_ = 1e-5f;
constexpr int TPB = 64 * R_;        // 640: wave w <-> rate w
constexpr int NCHUNK = (T_ + 511) / 512;   // 8

__global__ __launch_bounds__(TPB) void pcen_kernel(
    const float* __restrict__ x,
    const float* __restrict__ s_log,
    const float* __restrict__ alpha_log,
    const float* __restrict__ delta_log,
    const float* __restrict__ r_log,
    float* __restrict__ out)
{
    __shared__ float lds[2][512];

    const int lane = threadIdx.x & 63;
    const int rate = threadIdx.x >> 6;

    const int b = blockIdx.x / F_;
    const int f = blockIdx.x - b * F_;

    const float s     = __builtin_expf(s_log[rate * F_ + f]);
    const float a     = 1.0f - s;
    const float alpha = __builtin_expf(alpha_log[f]);
    const float delta = __builtin_expf(delta_log[f]);
    const float r     = __builtin_expf(r_log[f]);
    const float delta_r = __builtin_exp2f(r * __builtin_log2f(delta));

    const float a2 = a * a, a3 = a2 * a, a4 = a2 * a2;
    const float a8 = a4 * a4, a16 = a8 * a8, a32 = a16 * a16;
    const float a64 = a32 * a32, a128 = a64 * a64, a256 = a128 * a128;

    // per-lane a^(4*lane), exact product over lane bits
    float pl = 1.0f;
    pl *= (lane & 1)  ? a4   : 1.0f;
    pl *= (lane & 2)  ? a8   : 1.0f;
    pl *= (lane & 4)  ? a16  : 1.0f;
    pl *= (lane & 8)  ? a32  : 1.0f;
    pl *= (lane & 16) ? a64  : 1.0f;
    pl *= (lane & 32) ? a128 : 1.0f;

    const float* xrow = x   + (size_t)(b * F_ + f) * T_;
    float*       orow = out + (size_t)((b * R_ + rate) * F_ + f) * T_;

    float carry = xrow[0];   // y_{-1} := x_0  (a+s=1 makes y_0 = x_0)

    auto stage = [&](int k, int buf) {
        if (threadIdx.x < 128) {
            const int t = k * 512 + threadIdx.x * 4;
            float4 v = make_float4(0.f, 0.f, 0.f, 0.f);
            if (t < T_) v = *reinterpret_cast<const float4*>(xrow + t);
            *reinterpret_cast<float4*>(&lds[buf][threadIdx.x * 4]) = v;
        }
    };

    auto pcen1 = [&](float xv, float m) -> float {
        const float sm = __builtin_exp2f(-alpha * __builtin_log2f(EPS_ + m));
        return __builtin_exp2f(r * __builtin_log2f(fmaf(xv, sm, delta))) - delta_r;
    };

    stage(0, 0);
    __syncthreads();

    for (int k = 0; k < NCHUNK; ++k) {
        if (k + 1 < NCHUNK) stage(k + 1, (k + 1) & 1);

        const float* Lb = lds[k & 1];
        const float4 vA = *reinterpret_cast<const float4*>(Lb + lane * 4);
        const float4 vB = *reinterpret_cast<const float4*>(Lb + 256 + lane * 4);

        const int tA = k * 512 + lane * 4;
        const int tB = tA + 256;

        // local zero-init scans (independent)
        const float lA0 = s * vA.x;
        const float lA1 = fmaf(a, lA0, s * vA.y);
        const float lA2 = fmaf(a, lA1, s * vA.z);
        const float lA3 = fmaf(a, lA2, s * vA.w);
        const float lB0 = s * vB.x;
        const float lB1 = fmaf(a, lB0, s * vB.y);
        const float lB2 = fmaf(a, lB1, s * vB.z);
        const float lB3 = fmaf(a, lB2, s * vB.w);

        float YA = lA3;
        if (lane == 0) YA = fmaf(a4, carry, YA);   // fold prev-chunk carry
        float YB = lB3;                             // zero-init chain

        // two interleaved Hillis-Steele scans, segment multiplier a^4
        float uA, uB;
        uA = __shfl_up(YA, 1);  uB = __shfl_up(YB, 1);
        if (lane >= 1)  { YA = fmaf(a4,   uA, YA); YB = fmaf(a4,   uB, YB); }
        uA = __shfl_up(YA, 2);  uB = __shfl_up(YB, 2);
        if (lane >= 2)  { YA = fmaf(a8,   uA, YA); YB = fmaf(a8,   uB, YB); }
        uA = __shfl_up(YA, 4);  uB = __shfl_up(YB, 4);
        if (lane >= 4)  { YA = fmaf(a16,  uA, YA); YB = fmaf(a16,  uB, YB); }
        uA = __shfl_up(YA, 8);  uB = __shfl_up(YB, 8);
        if (lane >= 8)  { YA = fmaf(a32,  uA, YA); YB = fmaf(a32,  uB, YB); }
        uA = __shfl_up(YA, 16); uB = __shfl_up(YB, 16);
        if (lane >= 16) { YA = fmaf(a64,  uA, YA); YB = fmaf(a64,  uB, YB); }
        uA = __shfl_up(YA, 32); uB = __shfl_up(YB, 32);
        if (lane >= 32) { YA = fmaf(a128, uA, YA); YB = fmaf(a128, uB, YB); }

        float yinA = __shfl_up(YA, 1);
        if (lane == 0) yinA = carry;
        float yinB = __shfl_up(YB, 1);
        if (lane == 0) yinB = 0.0f;
        const float exitA = __shfl(YA, 63);
        yinB = fmaf(pl, exitA, yinB);              // link chain B to chain A
        carry = fmaf(a256, exitA, __shfl(YB, 63)); // chunk-exit state

        if (tA < T_) {
            const float mA0 = fmaf(a,  yinA, lA0);
            const float mA1 = fmaf(a2, yinA, lA1);
            const float mA2 = fmaf(a3, yinA, lA2);
            const float mA3 = fmaf(a4, yinA, lA3);
            f32x4 o;
            o.x = pcen1(vA.x, mA0);
            o.y = pcen1(vA.y, mA1);
            o.z = pcen1(vA.z, mA2);
            o.w = pcen1(vA.w, mA3);
            __builtin_nontemporal_store(o, reinterpret_cast<f32x4*>(orow + tA));
        }
        if (tB < T_) {
            const float mB0 = fmaf(a,  yinB, lB0);
            const float mB1 = fmaf(a2, yinB, lB1);
            const float mB2 = fmaf(a3, yinB, lB2);
            const float mB3 = fmaf(a4, yinB, lB3);
            f32x4 o;
            o.x = pcen1(vB.x, mB0);
            o.y = pcen1(vB.y, mB1);
            o.z = pcen1(vB.z, mB2);
            o.w = pcen1(vB.w, mB3);
            __builtin_nontemporal_store(o, reinterpret_cast<f32x4*>(orow + tB));
        }

        __syncthreads();   // protects buf[k&1] before stage(k+2) overwrites
    }
}

extern "C" void kernel_launch(void* const* d_in, const int* in_sizes, int n_in,
                              void* d_out, int out_size, void* d_ws, size_t ws_size,
                              hipStream_t stream) {
    const float* x         = (const float*)d_in[0];
    const float* s_log     = (const float*)d_in[1];
    const float* alpha_log = (const float*)d_in[2];
    const float* delta_log = (const float*)d_in[3];
    const float* r_log     = (const float*)d_in[4];
    float* out = (float*)d_out;

    const int blocks = B_ * F_;                // 2048 blocks, 10 waves each
    pcen_kernel<<<blocks, TPB, 0, stream>>>(x, s_log, alpha_log, delta_log, r_log, out);
}

// Round 9
// 93.960 us; speedup vs baseline: 1.1784x; 1.1564x over previous
//
#include <hip/hip_runtime.h>

// PCEN with 10 smoothing rates. x:(B,F,T) f32 -> out:(B,R,F,T) f32
//
// R9 = R6 (dual-chain scan, dense nt stores, rate-major, 1 wave = 1 row)
//      + readfirstlane on ALL wave-uniform scalars (powers, PCEN consts)
//      + __launch_bounds__(256, 4) to force VGPR<=128 -> 4 waves/SIMD.
// Theory: not throughput-bound anywhere (writes ~52us, VALU ~30us); the
// 91us plateau insensitive to store mode/density/read staging = latency-
// bound at ~2 waves/SIMD from VGPR pressure (per-rate constants live in
// VGPRs because compiler can't prove wave-uniformity of threadIdx>>6).
// History: R3 nt=90.8 | R4 5rates/wave=100.5 | R5 cached=117 | R6 nt
// dense=91.5 | R7 cached dense=110.7 | R8 LDS-staged=108.7.

typedef float f32x4 __attribute__((ext_vector_type(4)));

constexpr int B_ = 16, F_ = 128, T_ = 4000, R_ = 10;
constexpr float EPS_ = 1e-5f;
constexpr int TPB = 256;            // 4 waves / block
constexpr int WPB = TPB / 64;

__device__ __forceinline__ float rfl(float v) {
    return __int_as_float(__builtin_amdgcn_readfirstlane(__float_as_int(v)));
}

__global__ __launch_bounds__(TPB, 4) void pcen_kernel(
    const float* __restrict__ x,
    const float* __restrict__ s_log,
    const float* __restrict__ alpha_log,
    const float* __restrict__ delta_log,
    const float* __restrict__ r_log,
    float* __restrict__ out)
{
    const int wid  = blockIdx.x * WPB + (threadIdx.x >> 6);
    const int lane = threadIdx.x & 63;

    // rate-major: wid = ((b*R + rate)*F + f) -> block's 4 waves write 4
    // consecutive 16KB output rows.
    const int b    = wid / (R_ * F_);
    const int rem  = wid - b * (R_ * F_);
    const int rate = rem / F_;
    const int f    = rem - rate * F_;

    // ALL wave-uniform scalars forced to SGPRs via readfirstlane.
    const float s     = rfl(__builtin_expf(s_log[rate * F_ + f]));
    const float a     = rfl(1.0f - s);
    const float alpha = rfl(__builtin_expf(alpha_log[f]));
    const float delta = rfl(__builtin_expf(delta_log[f]));
    const float r     = rfl(__builtin_expf(r_log[f]));
    const float delta_r = rfl(__builtin_exp2f(r * __builtin_log2f(delta)));

    const float a2 = rfl(a * a);
    const float a3 = rfl(a2 * a);
    const float a4 = rfl(a2 * a2);
    const float a8 = rfl(a4 * a4);
    const float a16 = rfl(a8 * a8);
    const float a32 = rfl(a16 * a16);
    const float a64 = rfl(a32 * a32);
    const float a128 = rfl(a64 * a64);
    const float a256 = rfl(a128 * a128);

    // per-lane a^(4*lane), exact product over lane bits (VGPR, per-lane)
    float pl = 1.0f;
    pl *= (lane & 1)  ? a4   : 1.0f;
    pl *= (lane & 2)  ? a8   : 1.0f;
    pl *= (lane & 4)  ? a16  : 1.0f;
    pl *= (lane & 8)  ? a32  : 1.0f;
    pl *= (lane & 16) ? a64  : 1.0f;
    pl *= (lane & 32) ? a128 : 1.0f;

    const float* xrow = x   + (size_t)(b * F_ + f) * T_;
    float*       orow = out + (size_t)((b * R_ + rate) * F_ + f) * T_;

    float carry = xrow[0];   // y_{-1} := x_0  (a+s=1 makes y_0 = x_0)

    auto pcen1 = [&](float xv, float m) -> float {
        const float sm = __builtin_exp2f(-alpha * __builtin_log2f(EPS_ + m));
        return __builtin_exp2f(r * __builtin_log2f(fmaf(xv, sm, delta))) - delta_r;
    };

    for (int t0 = 0; t0 < T_; t0 += 512) {
        const int tA = t0 + lane * 4;
        const int tB = tA + 256;
        const bool actA = (tA < T_);
        const bool actB = (tB < T_);
        float4 vA = make_float4(0.f, 0.f, 0.f, 0.f);
        float4 vB = make_float4(0.f, 0.f, 0.f, 0.f);
        if (actA) vA = *reinterpret_cast<const float4*>(xrow + tA);
        if (actB) vB = *reinterpret_cast<const float4*>(xrow + tB);

        // local zero-init scans (independent)
        const float lA0 = s * vA.x;
        const float lA1 = fmaf(a, lA0, s * vA.y);
        const float lA2 = fmaf(a, lA1, s * vA.z);
        const float lA3 = fmaf(a, lA2, s * vA.w);
        const float lB0 = s * vB.x;
        const float lB1 = fmaf(a, lB0, s * vB.y);
        const float lB2 = fmaf(a, lB1, s * vB.z);
        const float lB3 = fmaf(a, lB2, s * vB.w);

        float YA = lA3;
        if (lane == 0) YA = fmaf(a4, carry, YA);   // fold prev-chunk carry
        float YB = lB3;                             // zero-init chain

        // two interleaved Hillis-Steele scans, segment multiplier a^4
        float uA, uB;
        uA = __shfl_up(YA, 1);  uB = __shfl_up(YB, 1);
        if (lane >= 1)  { YA = fmaf(a4,   uA, YA); YB = fmaf(a4,   uB, YB); }
        uA = __shfl_up(YA, 2);  uB = __shfl_up(YB, 2);
        if (lane >= 2)  { YA = fmaf(a8,   uA, YA); YB = fmaf(a8,   uB, YB); }
        uA = __shfl_up(YA, 4);  uB = __shfl_up(YB, 4);
        if (lane >= 4)  { YA = fmaf(a16,  uA, YA); YB = fmaf(a16,  uB, YB); }
        uA = __shfl_up(YA, 8);  uB = __shfl_up(YB, 8);
        if (lane >= 8)  { YA = fmaf(a32,  uA, YA); YB = fmaf(a32,  uB, YB); }
        uA = __shfl_up(YA, 16); uB = __shfl_up(YB, 16);
        if (lane >= 16) { YA = fmaf(a64,  uA, YA); YB = fmaf(a64,  uB, YB); }
        uA = __shfl_up(YA, 32); uB = __shfl_up(YB, 32);
        if (lane >= 32) { YA = fmaf(a128, uA, YA); YB = fmaf(a128, uB, YB); }

        float yinA = __shfl_up(YA, 1);
        if (lane == 0) yinA = carry;
        float yinB = __shfl_up(YB, 1);
        if (lane == 0) yinB = 0.0f;
        const float exitA = __shfl(YA, 63);
        yinB = fmaf(pl, exitA, yinB);              // link chain B to chain A
        carry = fmaf(a256, exitA, __shfl(YB, 63)); // chunk-exit state

        if (actA) {
            const float mA0 = fmaf(a,  yinA, lA0);
            const float mA1 = fmaf(a2, yinA, lA1);
            const float mA2 = fmaf(a3, yinA, lA2);
            const float mA3 = fmaf(a4, yinA, lA3);
            f32x4 o;
            o.x = pcen1(vA.x, mA0);
            o.y = pcen1(vA.y, mA1);
            o.z = pcen1(vA.z, mA2);
            o.w = pcen1(vA.w, mA3);
            __builtin_nontemporal_store(o, reinterpret_cast<f32x4*>(orow + tA));
        }
        if (actB) {
            const float mB0 = fmaf(a,  yinB, lB0);
            const float mB1 = fmaf(a2, yinB, lB1);
            const float mB2 = fmaf(a3, yinB, lB2);
            const float mB3 = fmaf(a4, yinB, lB3);
            f32x4 o;
            o.x = pcen1(vB.x, mB0);
            o.y = pcen1(vB.y, mB1);
            o.z = pcen1(vB.z, mB2);
            o.w = pcen1(vB.w, mB3);
            __builtin_nontemporal_store(o, reinterpret_cast<f32x4*>(orow + tB));
        }
    }
}

extern "C" void kernel_launch(void* const* d_in, const int* in_sizes, int n_in,
                              void* d_out, int out_size, void* d_ws, size_t ws_size,
                              hipStream_t stream) {
    const float* x         = (const float*)d_in[0];
    const float* s_log     = (const float*)d_in[1];
    const float* alpha_log = (const float*)d_in[2];
    const float* delta_log = (const float*)d_in[3];
    const float* r_log     = (const float*)d_in[4];
    float* out = (float*)d_out;

    const int n_waves = B_ * R_ * F_;          // 20480
    const int blocks  = n_waves / WPB;         // 5120
    pcen_kernel<<<blocks, TPB, 0, stream>>>(x, s_log, alpha_log, delta_log, r_log, out);
}